// Round 1
// baseline (779.135 us; speedup 1.0000x reference)
//
#include <hip/hip_runtime.h>

// MoE Transformer encoder layer, MI355X/gfx950.
// Strategy: fp32 gating (exact argmax), per-expert token routing, weights
// transposed+cast to bf16 once per launch (reused 67MB ws buffer), grouped
// bf16 MFMA GEMMs (16x16x32), flash attention with online softmax, fp32 LNs.

#define B_   2
#define N_   1024
#define D_   1024
#define H_   16
#define DH_  64
#define FF_  4096
#define E_   8
#define NTOK 2048

typedef __attribute__((ext_vector_type(8))) short short8;
typedef __attribute__((ext_vector_type(8))) unsigned short ushort8;
typedef __attribute__((ext_vector_type(4))) float f32x4;

__device__ inline unsigned short f2bf(float f) {
  unsigned u = __float_as_uint(f);
  u += 0x7FFFu + ((u >> 16) & 1u);   // round-to-nearest-even
  return (unsigned short)(u >> 16);
}

__device__ inline float gelu_tanh(float x) {
  float x3 = x * x * x;
  float t = tanhf(0.7978845608028654f * (x + 0.044715f * x3));
  return 0.5f * x * (1.0f + t);
}

// ---------------- gating: one wave per token, fp32 exact ----------------
__global__ __launch_bounds__(256) void gate_kernel(
    const float* __restrict__ X, const float* __restrict__ Wg,
    int* __restrict__ idx, float* __restrict__ gwv, int* __restrict__ cnt) {
  int t = blockIdx.x * 4 + (threadIdx.x >> 6);
  int lane = threadIdx.x & 63;
  const float* x = X + (size_t)t * D_;
  float acc[E_];
#pragma unroll
  for (int j = 0; j < E_; j++) acc[j] = 0.f;
#pragma unroll
  for (int i = 0; i < 16; i++) {
    int d = i * 64 + lane;
    float xv = x[d];
    const float4* w = (const float4*)(Wg + (size_t)d * E_);
    float4 w0 = w[0], w1 = w[1];
    acc[0] += xv * w0.x; acc[1] += xv * w0.y; acc[2] += xv * w0.z; acc[3] += xv * w0.w;
    acc[4] += xv * w1.x; acc[5] += xv * w1.y; acc[6] += xv * w1.z; acc[7] += xv * w1.w;
  }
#pragma unroll
  for (int o = 1; o < 64; o <<= 1) {
#pragma unroll
    for (int j = 0; j < E_; j++) acc[j] += __shfl_xor(acc[j], o, 64);
  }
  float m = acc[0]; int bi = 0;
#pragma unroll
  for (int j = 1; j < E_; j++) { if (acc[j] > m) { m = acc[j]; bi = j; } }  // first-max = jnp.argmax
  float den = 0.f;
#pragma unroll
  for (int j = 0; j < E_; j++) den += expf(acc[j] - m);
  float gw = expf(acc[bi] - m) / den;
  if (lane == 0) { idx[t] = bi; gwv[t] = gw; atomicAdd(&cnt[bi], 1); }
}

// ---------------- routing: single block builds per-expert lists ----------------
__global__ __launch_bounds__(256) void route_kernel(
    const int* __restrict__ idx, const int* __restrict__ cnt,
    int* __restrict__ off, int* __restrict__ perm, int ntok) {
  __shared__ int loff[E_ + 1];
  __shared__ int lfill[E_];
  if (threadIdx.x == 0) {
    int s = 0;
    for (int e = 0; e < E_; e++) { loff[e] = s; s += cnt[e]; }
    loff[E_] = s;
  }
  if (threadIdx.x < E_) lfill[threadIdx.x] = 0;
  __syncthreads();
  for (int t = (int)threadIdx.x; t < ntok; t += 256) {
    int e = idx[t];
    int p = atomicAdd(&lfill[e], 1);
    perm[loff[e] + p] = t;
  }
  if (threadIdx.x < E_ + 1) off[threadIdx.x] = loff[threadIdx.x];
}

// ---------------- weight transpose + bf16 cast: W[E][K][N] -> WT[E][N][K] ----------------
__global__ __launch_bounds__(256) void transpose_w_kernel(
    const float* __restrict__ W, unsigned short* __restrict__ WT, int K, int N) {
  __shared__ float T[64][68];
  int e = blockIdx.z;
  int n0 = blockIdx.x * 64, k0 = blockIdx.y * 64;
  int tid = threadIdx.x;
  {
    int kr = tid >> 4;
    int nc = (tid & 15) * 4;
#pragma unroll
    for (int j = 0; j < 4; j++) {
      int k = kr + j * 16;
      float4 v = *(const float4*)(W + ((size_t)e * K + k0 + k) * N + n0 + nc);
      *(float4*)&T[k][nc] = v;
    }
  }
  __syncthreads();
  {
    int n = tid >> 2;
    int ko = (tid & 3) * 16;
    ushort8 o0, o1;
#pragma unroll
    for (int i = 0; i < 8; i++) o0[i] = f2bf(T[ko + i][n]);
#pragma unroll
    for (int i = 0; i < 8; i++) o1[i] = f2bf(T[ko + 8 + i][n]);
    unsigned short* p = WT + ((size_t)e * N + n0 + n) * K + k0 + ko;
    *(ushort8*)p = o0;
    *(ushort8*)(p + 8) = o1;
  }
}

// ---------------- grouped MoE GEMM: out[t][n] = act((A[t]·WT[e] + bias)·gw) ----------------
// A gathered by perm within expert block; 128x128x32 tiles, 4 waves of 64x64.
template <typename AT, bool GELU, bool OBF16>
__global__ __launch_bounds__(256) void gemm_kernel(
    const AT* __restrict__ A, int ldA,
    const unsigned short* __restrict__ WT, const float* __restrict__ bias,
    const float* __restrict__ gwv, const int* __restrict__ perm, const int* __restrict__ off,
    void* __restrict__ out, int ldO, int K, int N) {
  __shared__ __align__(16) unsigned short As[128][40];  // stride 80B: 16B-aligned frags, ~2-way banks
  __shared__ __align__(16) unsigned short Bs[128][40];
  __shared__ int toks[128];
  __shared__ float gws[128];

  int e = blockIdx.y;
  int base = off[e];
  int cnt = off[e + 1] - base;
  int m0 = blockIdx.z * 128;
  if (m0 >= cnt) return;
  int rows_valid = min(128, cnt - m0);
  int tid = threadIdx.x;
  if (tid < 128) {
    int r = (tid < rows_valid) ? tid : (rows_valid - 1);
    int t = perm[base + m0 + r];
    toks[tid] = t;
    gws[tid] = gwv[t];
  }
  int nb = blockIdx.x * 128;
  int lane = tid & 63, wave = tid >> 6;
  int wm = (wave >> 1) * 64, wn = (wave & 1) * 64;
  int lr = lane & 15, lg = lane >> 4;
  f32x4 acc[4][4];
#pragma unroll
  for (int m = 0; m < 4; m++)
#pragma unroll
    for (int n = 0; n < 4; n++) acc[m][n] = (f32x4){0.f, 0.f, 0.f, 0.f};
  int srow = tid >> 1, koff = (tid & 1) * 16;
  __syncthreads();

  for (int k0 = 0; k0 < K; k0 += 32) {
    // stage A (gathered rows, cvt to bf16 if fp32)
    {
      const AT* ar = A + (size_t)toks[srow] * ldA + k0 + koff;
      ushort8 o0, o1;
      if constexpr (sizeof(AT) == 4) {
        const float* fa = (const float*)ar;
        float4 v0 = *(const float4*)(fa);
        float4 v1 = *(const float4*)(fa + 4);
        float4 v2 = *(const float4*)(fa + 8);
        float4 v3 = *(const float4*)(fa + 12);
        o0[0] = f2bf(v0.x); o0[1] = f2bf(v0.y); o0[2] = f2bf(v0.z); o0[3] = f2bf(v0.w);
        o0[4] = f2bf(v1.x); o0[5] = f2bf(v1.y); o0[6] = f2bf(v1.z); o0[7] = f2bf(v1.w);
        o1[0] = f2bf(v2.x); o1[1] = f2bf(v2.y); o1[2] = f2bf(v2.z); o1[3] = f2bf(v2.w);
        o1[4] = f2bf(v3.x); o1[5] = f2bf(v3.y); o1[6] = f2bf(v3.z); o1[7] = f2bf(v3.w);
      } else {
        o0 = *(const ushort8*)ar;
        o1 = *(const ushort8*)(ar + 8);
      }
      *(ushort8*)&As[srow][koff] = o0;
      *(ushort8*)&As[srow][koff + 8] = o1;
      // stage B from pre-transposed bf16 weights (k-contiguous rows)
      const unsigned short* br = WT + ((size_t)e * N + nb + srow) * K + k0 + koff;
      *(ushort8*)&Bs[srow][koff] = *(const ushort8*)br;
      *(ushort8*)&Bs[srow][koff + 8] = *(const ushort8*)(br + 8);
    }
    __syncthreads();
    short8 av[4], bv[4];
#pragma unroll
    for (int m = 0; m < 4; m++) av[m] = *(const short8*)&As[wm + m * 16 + lr][lg * 8];
#pragma unroll
    for (int n = 0; n < 4; n++) bv[n] = *(const short8*)&Bs[wn + n * 16 + lr][lg * 8];
#pragma unroll
    for (int m = 0; m < 4; m++)
#pragma unroll
      for (int n = 0; n < 4; n++)
        acc[m][n] = __builtin_amdgcn_mfma_f32_16x16x32_bf16(av[m], bv[n], acc[m][n], 0, 0, 0);
    __syncthreads();
  }

  // epilogue: bias + gate-weight (+ gelu), scatter rows back by token id
#pragma unroll
  for (int n = 0; n < 4; n++) {
    int col = wn + n * 16 + lr;
    float bvs = bias[(size_t)e * N + nb + col];
#pragma unroll
    for (int m = 0; m < 4; m++) {
#pragma unroll
      for (int reg = 0; reg < 4; reg++) {
        int r = wm + m * 16 + lg * 4 + reg;
        if (r < rows_valid) {
          int t = toks[r];
          float val = (acc[m][n][reg] + bvs) * gws[r];
          if constexpr (GELU) val = gelu_tanh(val);
          if constexpr (OBF16)
            ((unsigned short*)out)[(size_t)t * ldO + nb + col] = f2bf(val);
          else
            ((float*)out)[(size_t)t * ldO + nb + col] = val;
        }
      }
    }
  }
}

// ---------------- V transpose per (b,h): qkv v-part -> vT[bh][dh][token] ----------------
__global__ __launch_bounds__(256) void vtrans_kernel(
    const unsigned short* __restrict__ qkv, unsigned short* __restrict__ vT) {
  __shared__ __align__(16) unsigned short T[64][72];
  int bh = blockIdx.x;
  int b = bh >> 4, h = bh & 15;
  int tile = blockIdx.y;
  int tid = threadIdx.x;
  {
    int tk = tid >> 2, dof = (tid & 3) * 16;
    const unsigned short* p =
        qkv + ((size_t)(b * N_ + tile * 64 + tk)) * 3072 + 2048 + h * 64 + dof;
    *(ushort8*)&T[tk][dof] = *(const ushort8*)p;
    *(ushort8*)&T[tk][dof + 8] = *(const ushort8*)(p + 8);
  }
  __syncthreads();
  {
    int dh = tid >> 2, tof = (tid & 3) * 16;
    ushort8 o0, o1;
#pragma unroll
    for (int i = 0; i < 8; i++) o0[i] = T[tof + i][dh];
#pragma unroll
    for (int i = 0; i < 8; i++) o1[i] = T[tof + 8 + i][dh];
    unsigned short* q = vT + ((size_t)bh * 64 + dh) * N_ + tile * 64 + tof;
    *(ushort8*)q = o0;
    *(ushort8*)(q + 8) = o1;
  }
}

// ---------------- flash attention: Q-tile 64 per (b,h), online softmax ----------------
__global__ __launch_bounds__(256) void attn_kernel(
    const unsigned short* __restrict__ qkv, const unsigned short* __restrict__ vT,
    const unsigned char* __restrict__ kpm, unsigned short* __restrict__ ctx) {
  __shared__ __align__(16) unsigned short Qs[64][72];
  __shared__ __align__(16) unsigned short Ks[64][72];
  __shared__ __align__(16) unsigned short Vs[64][72];
  __shared__ __align__(16) unsigned short Ps[4][16][72];
  __shared__ float maskf[64];
  int qt = blockIdx.x, bh = blockIdx.y;
  int b = bh >> 4, h = bh & 15;
  int tid = threadIdx.x, lane = tid & 63, wave = tid >> 6;
  int lr = lane & 15, lg = lane >> 4;
  {
    int r = tid >> 2, dof = (tid & 3) * 16;
    const unsigned short* p = qkv + ((size_t)(b * N_ + qt * 64 + r)) * 3072 + h * 64 + dof;
    *(ushort8*)&Qs[r][dof] = *(const ushort8*)p;
    *(ushort8*)&Qs[r][dof + 8] = *(const ushort8*)(p + 8);
  }
  __syncthreads();
  short8 aq[2];
  aq[0] = *(const short8*)&Qs[wave * 16 + lr][lg * 8];
  aq[1] = *(const short8*)&Qs[wave * 16 + lr][32 + lg * 8];
  f32x4 O[4];
  float mrun[4], lrun[4];
#pragma unroll
  for (int r = 0; r < 4; r++) { mrun[r] = -1e30f; lrun[r] = 0.f; O[r] = (f32x4){0.f, 0.f, 0.f, 0.f}; }

  for (int kt = 0; kt < 16; kt++) {
    __syncthreads();
    {
      int r = tid >> 2, dof = (tid & 3) * 16;
      const unsigned short* p =
          qkv + ((size_t)(b * N_ + kt * 64 + r)) * 3072 + 1024 + h * 64 + dof;
      *(ushort8*)&Ks[r][dof] = *(const ushort8*)p;
      *(ushort8*)&Ks[r][dof + 8] = *(const ushort8*)(p + 8);
      const unsigned short* pv = vT + ((size_t)bh * 64 + r) * N_ + kt * 64 + dof;
      *(ushort8*)&Vs[r][dof] = *(const ushort8*)pv;
      *(ushort8*)&Vs[r][dof + 8] = *(const ushort8*)(pv + 8);
      if (tid < 64) maskf[tid] = kpm[b * N_ + kt * 64 + tid] ? -10000.f : 0.f;
    }
    __syncthreads();
    f32x4 S[4];
#pragma unroll
    for (int n = 0; n < 4; n++) {
      f32x4 s = (f32x4){0.f, 0.f, 0.f, 0.f};
#pragma unroll
      for (int ks = 0; ks < 2; ks++) {
        short8 bk = *(const short8*)&Ks[n * 16 + lr][ks * 32 + lg * 8];
        s = __builtin_amdgcn_mfma_f32_16x16x32_bf16(aq[ks], bk, s, 0, 0, 0);
      }
      float mv = maskf[n * 16 + lr];
#pragma unroll
      for (int r = 0; r < 4; r++) s[r] = s[r] * 0.125f + mv;
      S[n] = s;
    }
    float cur[4];
#pragma unroll
    for (int r = 0; r < 4; r++)
      cur[r] = fmaxf(fmaxf(S[0][r], S[1][r]), fmaxf(S[2][r], S[3][r]));
#pragma unroll
    for (int o = 1; o < 16; o <<= 1) {
#pragma unroll
      for (int r = 0; r < 4; r++) cur[r] = fmaxf(cur[r], __shfl_xor(cur[r], o, 64));
    }
    float alpha[4], rsum[4];
#pragma unroll
    for (int r = 0; r < 4; r++) {
      float mn = fmaxf(mrun[r], cur[r]);
      alpha[r] = expf(mrun[r] - mn);
      mrun[r] = mn;
      rsum[r] = 0.f;
    }
#pragma unroll
    for (int n = 0; n < 4; n++) {
#pragma unroll
      for (int r = 0; r < 4; r++) {
        S[n][r] = expf(S[n][r] - mrun[r]);
        rsum[r] += S[n][r];
      }
    }
#pragma unroll
    for (int o = 1; o < 16; o <<= 1) {
#pragma unroll
      for (int r = 0; r < 4; r++) rsum[r] += __shfl_xor(rsum[r], o, 64);
    }
#pragma unroll
    for (int r = 0; r < 4; r++) lrun[r] = lrun[r] * alpha[r] + rsum[r];
#pragma unroll
    for (int d = 0; d < 4; d++)
#pragma unroll
      for (int r = 0; r < 4; r++) O[d][r] *= alpha[r];
    // P (C-layout) -> per-wave LDS -> A-layout frags
#pragma unroll
    for (int n = 0; n < 4; n++)
#pragma unroll
      for (int r = 0; r < 4; r++) Ps[wave][lg * 4 + r][n * 16 + lr] = f2bf(S[n][r]);
    short8 pf[2];
    pf[0] = *(const short8*)&Ps[wave][lr][lg * 8];
    pf[1] = *(const short8*)&Ps[wave][lr][32 + lg * 8];
#pragma unroll
    for (int d = 0; d < 4; d++) {
#pragma unroll
      for (int ks = 0; ks < 2; ks++) {
        short8 bv = *(const short8*)&Vs[d * 16 + lr][ks * 32 + lg * 8];
        O[d] = __builtin_amdgcn_mfma_f32_16x16x32_bf16(pf[ks], bv, O[d], 0, 0, 0);
      }
    }
  }
#pragma unroll
  for (int r = 0; r < 4; r++) lrun[r] = 1.f / lrun[r];
#pragma unroll
  for (int d = 0; d < 4; d++) {
#pragma unroll
    for (int r = 0; r < 4; r++) {
      int q = qt * 64 + wave * 16 + lg * 4 + r;
      int dh = d * 16 + lr;
      ctx[((size_t)(b * N_ + q)) * D_ + h * DH_ + dh] = f2bf(O[d][r] * lrun[r]);
    }
  }
}

// ---------------- layernorm: out = LN(a + b) * s + bi ----------------
__global__ __launch_bounds__(256) void ln_kernel(
    const float* __restrict__ A, const float* __restrict__ Bv,
    const float* __restrict__ S, const float* __restrict__ Bi, float* __restrict__ O) {
  int t = blockIdx.x, tid = threadIdx.x;
  float4 va = ((const float4*)(A + (size_t)t * D_))[tid];
  float4 vb = ((const float4*)(Bv + (size_t)t * D_))[tid];
  float4 v;
  v.x = va.x + vb.x; v.y = va.y + vb.y; v.z = va.z + vb.z; v.w = va.w + vb.w;
  float s = v.x + v.y + v.z + v.w;
  float sq = v.x * v.x + v.y * v.y + v.z * v.z + v.w * v.w;
#pragma unroll
  for (int o = 1; o < 64; o <<= 1) {
    s += __shfl_xor(s, o, 64);
    sq += __shfl_xor(sq, o, 64);
  }
  __shared__ float ss[4], ssq[4];
  int wave = tid >> 6, lane = tid & 63;
  if (lane == 0) { ss[wave] = s; ssq[wave] = sq; }
  __syncthreads();
  float ts = ss[0] + ss[1] + ss[2] + ss[3];
  float tsq = ssq[0] + ssq[1] + ssq[2] + ssq[3];
  float mean = ts * (1.f / D_);
  float var = tsq * (1.f / D_) - mean * mean;
  float rs = rsqrtf(var + 1e-5f);
  float4 sv = ((const float4*)S)[tid];
  float4 bv = ((const float4*)Bi)[tid];
  float4 o;
  o.x = (v.x - mean) * rs * sv.x + bv.x;
  o.y = (v.y - mean) * rs * sv.y + bv.y;
  o.z = (v.z - mean) * rs * sv.z + bv.z;
  o.w = (v.w - mean) * rs * sv.w + bv.w;
  ((float4*)(O + (size_t)t * D_))[tid] = o;
}

extern "C" void kernel_launch(void* const* d_in, const int* in_sizes, int n_in,
                              void* d_out, int out_size, void* d_ws, size_t ws_size,
                              hipStream_t stream) {
  (void)in_sizes; (void)n_in; (void)out_size; (void)ws_size;
  const float* src     = (const float*)d_in[0];
  const unsigned char* kpm = (const unsigned char*)d_in[1];
  const float* Wg_attn = (const float*)d_in[2];
  const float* Wqkv    = (const float*)d_in[3];
  const float* bqkv    = (const float*)d_in[4];
  const float* Wo      = (const float*)d_in[5];
  const float* bo      = (const float*)d_in[6];
  const float* Wg_ffn  = (const float*)d_in[7];
  const float* W1      = (const float*)d_in[8];
  const float* b1      = (const float*)d_in[9];
  const float* W2      = (const float*)d_in[10];
  const float* b2      = (const float*)d_in[11];
  const float* ln1_s   = (const float*)d_in[12];
  const float* ln1_b   = (const float*)d_in[13];
  const float* ln2_s   = (const float*)d_in[14];
  const float* ln2_b   = (const float*)d_in[15];
  float* out = (float*)d_out;

  char* ws = (char*)d_ws;
  size_t o = 0;
  auto alloc = [&](size_t bytes) -> void* {
    void* p = ws + o;
    o += (bytes + 255) & ~(size_t)255;
    return p;
  };
  int* meta = (int*)alloc(256);  // cnt1[8] off1[9] cnt2[8] off2[9]
  int* cnt1 = meta;
  int* off1 = meta + 8;
  int* cnt2 = meta + 17;
  int* off2 = meta + 25;
  int* idx1 = (int*)alloc(NTOK * 4);
  float* gw1 = (float*)alloc(NTOK * 4);
  int* perm1 = (int*)alloc(NTOK * 4);
  int* idx2 = (int*)alloc(NTOK * 4);
  float* gw2 = (float*)alloc(NTOK * 4);
  int* perm2 = (int*)alloc(NTOK * 4);
  unsigned short* WT = (unsigned short*)alloc((size_t)E_ * FF_ * D_ * 2);     // 67.1 MB, reused 4x
  unsigned short* qkvb = (unsigned short*)alloc((size_t)NTOK * 3072 * 2);     // 12.6 MB
  unsigned short* vT = (unsigned short*)alloc((size_t)32 * 64 * N_ * 2);      // 4.2 MB (contig after qkvb)
  unsigned short* hbuf = qkvb;  // h[2048][4096] bf16 reuses qkv+vT (exactly 16.78 MB)
  unsigned short* ctx = (unsigned short*)alloc((size_t)NTOK * D_ * 2);
  float* attn_out = (float*)alloc((size_t)NTOK * D_ * 4);
  float* ffn = attn_out;  // reuse after LN1
  float* x = (float*)alloc((size_t)NTOK * D_ * 4);

  hipMemsetAsync(meta, 0, 256, stream);

  // --- MoE attention ---
  gate_kernel<<<512, 256, 0, stream>>>(src, Wg_attn, idx1, gw1, cnt1);
  route_kernel<<<1, 256, 0, stream>>>(idx1, cnt1, off1, perm1, NTOK);
  transpose_w_kernel<<<dim3(3072 / 64, 1024 / 64, 8), 256, 0, stream>>>(Wqkv, WT, 1024, 3072);
  gemm_kernel<float, false, true><<<dim3(3072 / 128, 8, 16), 256, 0, stream>>>(
      src, 1024, WT, bqkv, gw1, perm1, off1, qkvb, 3072, 1024, 3072);
  vtrans_kernel<<<dim3(32, 16), 256, 0, stream>>>(qkvb, vT);
  attn_kernel<<<dim3(16, 32), 256, 0, stream>>>(qkvb, vT, kpm, ctx);
  transpose_w_kernel<<<dim3(1024 / 64, 1024 / 64, 8), 256, 0, stream>>>(Wo, WT, 1024, 1024);
  gemm_kernel<unsigned short, false, false><<<dim3(1024 / 128, 8, 16), 256, 0, stream>>>(
      ctx, 1024, WT, bo, gw1, perm1, off1, attn_out, 1024, 1024, 1024);
  ln_kernel<<<NTOK, 256, 0, stream>>>(src, attn_out, ln1_s, ln1_b, x);

  // --- MoE FFN ---
  gate_kernel<<<512, 256, 0, stream>>>(x, Wg_ffn, idx2, gw2, cnt2);
  route_kernel<<<1, 256, 0, stream>>>(idx2, cnt2, off2, perm2, NTOK);
  transpose_w_kernel<<<dim3(4096 / 64, 1024 / 64, 8), 256, 0, stream>>>(W1, WT, 1024, 4096);
  gemm_kernel<float, true, true><<<dim3(4096 / 128, 8, 16), 256, 0, stream>>>(
      x, 1024, WT, b1, gw2, perm2, off2, hbuf, 4096, 1024, 4096);
  transpose_w_kernel<<<dim3(1024 / 64, 4096 / 64, 8), 256, 0, stream>>>(W2, WT, 4096, 1024);
  gemm_kernel<unsigned short, false, false><<<dim3(1024 / 128, 8, 16), 256, 0, stream>>>(
      hbuf, 4096, WT, b2, gw2, perm2, off2, ffn, 1024, 4096, 1024);
  ln_kernel<<<NTOK, 256, 0, stream>>>(x, ffn, ln2_s, ln2_b, out);
}

// Round 2
// 748.225 us; speedup vs baseline: 1.0413x; 1.0413x over previous
//
#include <hip/hip_runtime.h>

// MoE Transformer encoder layer, MI355X/gfx950.
// R2: split-K grouped GEMM (fixes 0.5 blocks/CU latency-bound K-loops seen in
// rocprof: MfmaUtil 6.5%, Occupancy 6.6%), fp32 partials + fused reduce
// epilogues (bias+gate+gelu; Wo/FFN2 reduce fused into the LayerNorms),
// transpose phase-2 bank-conflict fix (4-way -> 2-way).

#define B_   2
#define N_   1024
#define D_   1024
#define H_   16
#define DH_  64
#define FF_  4096
#define E_   8
#define NTOK 2048

typedef __attribute__((ext_vector_type(8))) short short8;
typedef __attribute__((ext_vector_type(8))) unsigned short ushort8;
typedef __attribute__((ext_vector_type(4))) unsigned short ushort4v;
typedef __attribute__((ext_vector_type(4))) float f32x4;

__device__ inline unsigned short f2bf(float f) {
  unsigned u = __float_as_uint(f);
  u += 0x7FFFu + ((u >> 16) & 1u);   // round-to-nearest-even
  return (unsigned short)(u >> 16);
}

__device__ inline float gelu_tanh(float x) {
  float x3 = x * x * x;
  float t = tanhf(0.7978845608028654f * (x + 0.044715f * x3));
  return 0.5f * x * (1.0f + t);
}

// ---------------- gating: one wave per token, fp32 exact ----------------
__global__ __launch_bounds__(256) void gate_kernel(
    const float* __restrict__ X, const float* __restrict__ Wg,
    int* __restrict__ idx, float* __restrict__ gwv, int* __restrict__ cnt) {
  int t = blockIdx.x * 4 + (threadIdx.x >> 6);
  int lane = threadIdx.x & 63;
  const float* x = X + (size_t)t * D_;
  float acc[E_];
#pragma unroll
  for (int j = 0; j < E_; j++) acc[j] = 0.f;
#pragma unroll
  for (int i = 0; i < 16; i++) {
    int d = i * 64 + lane;
    float xv = x[d];
    const float4* w = (const float4*)(Wg + (size_t)d * E_);
    float4 w0 = w[0], w1 = w[1];
    acc[0] += xv * w0.x; acc[1] += xv * w0.y; acc[2] += xv * w0.z; acc[3] += xv * w0.w;
    acc[4] += xv * w1.x; acc[5] += xv * w1.y; acc[6] += xv * w1.z; acc[7] += xv * w1.w;
  }
#pragma unroll
  for (int o = 1; o < 64; o <<= 1) {
#pragma unroll
    for (int j = 0; j < E_; j++) acc[j] += __shfl_xor(acc[j], o, 64);
  }
  float m = acc[0]; int bi = 0;
#pragma unroll
  for (int j = 1; j < E_; j++) { if (acc[j] > m) { m = acc[j]; bi = j; } }
  float den = 0.f;
#pragma unroll
  for (int j = 0; j < E_; j++) den += expf(acc[j] - m);
  float gw = expf(acc[bi] - m) / den;
  if (lane == 0) { idx[t] = bi; gwv[t] = gw; atomicAdd(&cnt[bi], 1); }
}

// ---------------- routing: single block builds per-expert lists ----------------
__global__ __launch_bounds__(256) void route_kernel(
    const int* __restrict__ idx, const int* __restrict__ cnt,
    int* __restrict__ off, int* __restrict__ perm, int ntok) {
  __shared__ int loff[E_ + 1];
  __shared__ int lfill[E_];
  if (threadIdx.x == 0) {
    int s = 0;
    for (int e = 0; e < E_; e++) { loff[e] = s; s += cnt[e]; }
    loff[E_] = s;
  }
  if (threadIdx.x < E_) lfill[threadIdx.x] = 0;
  __syncthreads();
  for (int t = (int)threadIdx.x; t < ntok; t += 256) {
    int e = idx[t];
    int p = atomicAdd(&lfill[e], 1);
    perm[loff[e] + p] = t;
  }
  if (threadIdx.x < E_ + 1) off[threadIdx.x] = loff[threadIdx.x];
}

// ---------------- weight transpose + bf16 cast: W[E][K][N] -> WT[E][N][K] ----------------
__global__ __launch_bounds__(256) void transpose_w_kernel(
    const float* __restrict__ W, unsigned short* __restrict__ WT, int K, int N) {
  __shared__ float T[64][68];
  int e = blockIdx.z;
  int n0 = blockIdx.x * 64, k0 = blockIdx.y * 64;
  int tid = threadIdx.x;
  {
    int kr = tid >> 4;
    int nc = (tid & 15) * 4;
#pragma unroll
    for (int j = 0; j < 4; j++) {
      int k = kr + j * 16;
      float4 v = *(const float4*)(W + ((size_t)e * K + k0 + k) * N + n0 + nc);
      *(float4*)&T[k][nc] = v;
    }
  }
  __syncthreads();
  {
    // n = tid&63: 64 distinct n per wave -> stride-68 fp32 reads are 2-way (free)
    int n = tid & 63;
    int ko = (tid >> 6) * 16;
    ushort8 o0, o1;
#pragma unroll
    for (int i = 0; i < 8; i++) o0[i] = f2bf(T[ko + i][n]);
#pragma unroll
    for (int i = 0; i < 8; i++) o1[i] = f2bf(T[ko + 8 + i][n]);
    unsigned short* p = WT + ((size_t)e * N + n0 + n) * K + k0 + ko;
    *(ushort8*)p = o0;
    *(ushort8*)(p + 8) = o1;
  }
}

// ---------------- grouped MoE GEMM with split-K, fp32 partial output ----------------
// part[kc][t][n] += A[t]·WT[e][n], kc = K-chunk. 128x128x32 tiles, 4 waves.
template <typename AT, int KS>
__global__ __launch_bounds__(256) void gemm_kernel(
    const AT* __restrict__ A, int ldA,
    const unsigned short* __restrict__ WT,
    const int* __restrict__ perm, const int* __restrict__ off,
    float* __restrict__ part, int K, int N) {
  __shared__ __align__(16) unsigned short As[128][40];
  __shared__ __align__(16) unsigned short Bs[128][40];
  __shared__ int toks[128];

  int e = blockIdx.y;
  int base = off[e];
  int cnt = off[e + 1] - base;
  int mt = blockIdx.z / KS;
  int kc = blockIdx.z % KS;
  int m0 = mt * 128;
  if (m0 >= cnt) return;
  int rows_valid = min(128, cnt - m0);
  int tid = threadIdx.x;
  if (tid < 128) {
    int r = (tid < rows_valid) ? tid : (rows_valid - 1);
    toks[tid] = perm[base + m0 + r];
  }
  int nb = blockIdx.x * 128;
  int lane = tid & 63, wave = tid >> 6;
  int wm = (wave >> 1) * 64, wn = (wave & 1) * 64;
  int lr = lane & 15, lg = lane >> 4;
  f32x4 acc[4][4];
#pragma unroll
  for (int m = 0; m < 4; m++)
#pragma unroll
    for (int n = 0; n < 4; n++) acc[m][n] = (f32x4){0.f, 0.f, 0.f, 0.f};
  int srow = tid >> 1, koff = (tid & 1) * 16;
  int KL = K / KS;
  int kbeg = kc * KL;
  __syncthreads();

  for (int k0 = kbeg; k0 < kbeg + KL; k0 += 32) {
    {
      const AT* ar = A + (size_t)toks[srow] * ldA + k0 + koff;
      ushort8 o0, o1;
      if constexpr (sizeof(AT) == 4) {
        const float* fa = (const float*)ar;
        float4 v0 = *(const float4*)(fa);
        float4 v1 = *(const float4*)(fa + 4);
        float4 v2 = *(const float4*)(fa + 8);
        float4 v3 = *(const float4*)(fa + 12);
        o0[0] = f2bf(v0.x); o0[1] = f2bf(v0.y); o0[2] = f2bf(v0.z); o0[3] = f2bf(v0.w);
        o0[4] = f2bf(v1.x); o0[5] = f2bf(v1.y); o0[6] = f2bf(v1.z); o0[7] = f2bf(v1.w);
        o1[0] = f2bf(v2.x); o1[1] = f2bf(v2.y); o1[2] = f2bf(v2.z); o1[3] = f2bf(v2.w);
        o1[4] = f2bf(v3.x); o1[5] = f2bf(v3.y); o1[6] = f2bf(v3.z); o1[7] = f2bf(v3.w);
      } else {
        o0 = *(const ushort8*)ar;
        o1 = *(const ushort8*)(ar + 8);
      }
      *(ushort8*)&As[srow][koff] = o0;
      *(ushort8*)&As[srow][koff + 8] = o1;
      const unsigned short* br = WT + ((size_t)e * N + nb + srow) * K + k0 + koff;
      *(ushort8*)&Bs[srow][koff] = *(const ushort8*)br;
      *(ushort8*)&Bs[srow][koff + 8] = *(const ushort8*)(br + 8);
    }
    __syncthreads();
    short8 av[4], bv[4];
#pragma unroll
    for (int m = 0; m < 4; m++) av[m] = *(const short8*)&As[wm + m * 16 + lr][lg * 8];
#pragma unroll
    for (int n = 0; n < 4; n++) bv[n] = *(const short8*)&Bs[wn + n * 16 + lr][lg * 8];
#pragma unroll
    for (int m = 0; m < 4; m++)
#pragma unroll
      for (int n = 0; n < 4; n++)
        acc[m][n] = __builtin_amdgcn_mfma_f32_16x16x32_bf16(av[m], bv[n], acc[m][n], 0, 0, 0);
    __syncthreads();
  }

  float* pr = part + (size_t)kc * ((size_t)NTOK * N);
#pragma unroll
  for (int n = 0; n < 4; n++) {
    int col = nb + wn + n * 16 + lr;
#pragma unroll
    for (int m = 0; m < 4; m++) {
#pragma unroll
      for (int reg = 0; reg < 4; reg++) {
        int r = wm + m * 16 + lg * 4 + reg;
        if (r < rows_valid)
          pr[(size_t)toks[r] * N + col] = acc[m][n][reg];
      }
    }
  }
}

// ---------------- reduce partials + bias + gate (+gelu), cast ----------------
template <int KS, bool GELU, bool OBF16>
__global__ __launch_bounds__(256) void reduce_kernel(
    const float* __restrict__ part, const float* __restrict__ bias,
    const float* __restrict__ gwv, const int* __restrict__ idx,
    void* __restrict__ out, int N) {
  int t = blockIdx.y;
  int n = (blockIdx.x * 256 + threadIdx.x) * 4;
  int e = idx[t];
  float gw = gwv[t];
  const float* p = part + (size_t)t * N + n;
  float4 a = *(const float4*)p;
#pragma unroll
  for (int k = 1; k < KS; k++) {
    float4 q = *(const float4*)(p + (size_t)k * NTOK * N);
    a.x += q.x; a.y += q.y; a.z += q.z; a.w += q.w;
  }
  float4 bv = *(const float4*)(bias + (size_t)e * N + n);
  a.x = (a.x + bv.x) * gw; a.y = (a.y + bv.y) * gw;
  a.z = (a.z + bv.z) * gw; a.w = (a.w + bv.w) * gw;
  if constexpr (GELU) {
    a.x = gelu_tanh(a.x); a.y = gelu_tanh(a.y);
    a.z = gelu_tanh(a.z); a.w = gelu_tanh(a.w);
  }
  if constexpr (OBF16) {
    ushort4v o;
    o[0] = f2bf(a.x); o[1] = f2bf(a.y); o[2] = f2bf(a.z); o[3] = f2bf(a.w);
    *(ushort4v*)((unsigned short*)out + (size_t)t * N + n) = o;
  } else {
    *(float4*)((float*)out + (size_t)t * N + n) = a;
  }
}

// ---------------- V transpose per (b,h) ----------------
__global__ __launch_bounds__(256) void vtrans_kernel(
    const unsigned short* __restrict__ qkv, unsigned short* __restrict__ vT) {
  __shared__ __align__(16) unsigned short T[64][72];
  int bh = blockIdx.x;
  int b = bh >> 4, h = bh & 15;
  int tile = blockIdx.y;
  int tid = threadIdx.x;
  {
    int tk = tid >> 2, dof = (tid & 3) * 16;
    const unsigned short* p =
        qkv + ((size_t)(b * N_ + tile * 64 + tk)) * 3072 + 2048 + h * 64 + dof;
    *(ushort8*)&T[tk][dof] = *(const ushort8*)p;
    *(ushort8*)&T[tk][dof + 8] = *(const ushort8*)(p + 8);
  }
  __syncthreads();
  {
    int dh = tid >> 2, tof = (tid & 3) * 16;
    ushort8 o0, o1;
#pragma unroll
    for (int i = 0; i < 8; i++) o0[i] = T[tof + i][dh];
#pragma unroll
    for (int i = 0; i < 8; i++) o1[i] = T[tof + 8 + i][dh];
    unsigned short* q = vT + ((size_t)bh * 64 + dh) * N_ + tile * 64 + tof;
    *(ushort8*)q = o0;
    *(ushort8*)(q + 8) = o1;
  }
}

// ---------------- flash attention ----------------
__global__ __launch_bounds__(256) void attn_kernel(
    const unsigned short* __restrict__ qkv, const unsigned short* __restrict__ vT,
    const unsigned char* __restrict__ kpm, unsigned short* __restrict__ ctx) {
  __shared__ __align__(16) unsigned short Qs[64][72];
  __shared__ __align__(16) unsigned short Ks[64][72];
  __shared__ __align__(16) unsigned short Vs[64][72];
  __shared__ __align__(16) unsigned short Ps[4][16][72];
  __shared__ float maskf[64];
  int qt = blockIdx.x, bh = blockIdx.y;
  int b = bh >> 4, h = bh & 15;
  int tid = threadIdx.x, lane = tid & 63, wave = tid >> 6;
  int lr = lane & 15, lg = lane >> 4;
  {
    int r = tid >> 2, dof = (tid & 3) * 16;
    const unsigned short* p = qkv + ((size_t)(b * N_ + qt * 64 + r)) * 3072 + h * 64 + dof;
    *(ushort8*)&Qs[r][dof] = *(const ushort8*)p;
    *(ushort8*)&Qs[r][dof + 8] = *(const ushort8*)(p + 8);
  }
  __syncthreads();
  short8 aq[2];
  aq[0] = *(const short8*)&Qs[wave * 16 + lr][lg * 8];
  aq[1] = *(const short8*)&Qs[wave * 16 + lr][32 + lg * 8];
  f32x4 O[4];
  float mrun[4], lrun[4];
#pragma unroll
  for (int r = 0; r < 4; r++) { mrun[r] = -1e30f; lrun[r] = 0.f; O[r] = (f32x4){0.f, 0.f, 0.f, 0.f}; }

  for (int kt = 0; kt < 16; kt++) {
    __syncthreads();
    {
      int r = tid >> 2, dof = (tid & 3) * 16;
      const unsigned short* p =
          qkv + ((size_t)(b * N_ + kt * 64 + r)) * 3072 + 1024 + h * 64 + dof;
      *(ushort8*)&Ks[r][dof] = *(const ushort8*)p;
      *(ushort8*)&Ks[r][dof + 8] = *(const ushort8*)(p + 8);
      const unsigned short* pv = vT + ((size_t)bh * 64 + r) * N_ + kt * 64 + dof;
      *(ushort8*)&Vs[r][dof] = *(const ushort8*)pv;
      *(ushort8*)&Vs[r][dof + 8] = *(const ushort8*)(pv + 8);
      if (tid < 64) maskf[tid] = kpm[b * N_ + kt * 64 + tid] ? -10000.f : 0.f;
    }
    __syncthreads();
    f32x4 S[4];
#pragma unroll
    for (int n = 0; n < 4; n++) {
      f32x4 s = (f32x4){0.f, 0.f, 0.f, 0.f};
#pragma unroll
      for (int ks = 0; ks < 2; ks++) {
        short8 bk = *(const short8*)&Ks[n * 16 + lr][ks * 32 + lg * 8];
        s = __builtin_amdgcn_mfma_f32_16x16x32_bf16(aq[ks], bk, s, 0, 0, 0);
      }
      float mv = maskf[n * 16 + lr];
#pragma unroll
      for (int r = 0; r < 4; r++) s[r] = s[r] * 0.125f + mv;
      S[n] = s;
    }
    float cur[4];
#pragma unroll
    for (int r = 0; r < 4; r++)
      cur[r] = fmaxf(fmaxf(S[0][r], S[1][r]), fmaxf(S[2][r], S[3][r]));
#pragma unroll
    for (int o = 1; o < 16; o <<= 1) {
#pragma unroll
      for (int r = 0; r < 4; r++) cur[r] = fmaxf(cur[r], __shfl_xor(cur[r], o, 64));
    }
    float alpha[4], rsum[4];
#pragma unroll
    for (int r = 0; r < 4; r++) {
      float mn = fmaxf(mrun[r], cur[r]);
      alpha[r] = expf(mrun[r] - mn);
      mrun[r] = mn;
      rsum[r] = 0.f;
    }
#pragma unroll
    for (int n = 0; n < 4; n++) {
#pragma unroll
      for (int r = 0; r < 4; r++) {
        S[n][r] = expf(S[n][r] - mrun[r]);
        rsum[r] += S[n][r];
      }
    }
#pragma unroll
    for (int o = 1; o < 16; o <<= 1) {
#pragma unroll
      for (int r = 0; r < 4; r++) rsum[r] += __shfl_xor(rsum[r], o, 64);
    }
#pragma unroll
    for (int r = 0; r < 4; r++) lrun[r] = lrun[r] * alpha[r] + rsum[r];
#pragma unroll
    for (int d = 0; d < 4; d++)
#pragma unroll
      for (int r = 0; r < 4; r++) O[d][r] *= alpha[r];
#pragma unroll
    for (int n = 0; n < 4; n++)
#pragma unroll
      for (int r = 0; r < 4; r++) Ps[wave][lg * 4 + r][n * 16 + lr] = f2bf(S[n][r]);
    short8 pf[2];
    pf[0] = *(const short8*)&Ps[wave][lr][lg * 8];
    pf[1] = *(const short8*)&Ps[wave][lr][32 + lg * 8];
#pragma unroll
    for (int d = 0; d < 4; d++) {
#pragma unroll
      for (int ks = 0; ks < 2; ks++) {
        short8 bv = *(const short8*)&Vs[d * 16 + lr][ks * 32 + lg * 8];
        O[d] = __builtin_amdgcn_mfma_f32_16x16x32_bf16(pf[ks], bv, O[d], 0, 0, 0);
      }
    }
  }
#pragma unroll
  for (int r = 0; r < 4; r++) lrun[r] = 1.f / lrun[r];
#pragma unroll
  for (int d = 0; d < 4; d++) {
#pragma unroll
    for (int r = 0; r < 4; r++) {
      int q = qt * 64 + wave * 16 + lg * 4 + r;
      int dh = d * 16 + lr;
      ctx[((size_t)(b * N_ + q)) * D_ + h * DH_ + dh] = f2bf(O[d][r] * lrun[r]);
    }
  }
}

// ---------------- fused: out = LN(res + (Σ part + bias)·gw) ----------------
template <int KS>
__global__ __launch_bounds__(256) void ln_reduce_kernel(
    const float* __restrict__ res, const float* __restrict__ part,
    const float* __restrict__ bias, const float* __restrict__ gwv,
    const int* __restrict__ idx,
    const float* __restrict__ S, const float* __restrict__ Bi,
    float* __restrict__ O) {
  int t = blockIdx.x, tid = threadIdx.x;
  int e = idx[t];
  float gw = gwv[t];
  const float* p = part + (size_t)t * D_ + tid * 4;
  float4 a = *(const float4*)p;
#pragma unroll
  for (int k = 1; k < KS; k++) {
    float4 q = *(const float4*)(p + (size_t)k * NTOK * D_);
    a.x += q.x; a.y += q.y; a.z += q.z; a.w += q.w;
  }
  float4 bv4 = *(const float4*)(bias + (size_t)e * D_ + tid * 4);
  float4 vr = ((const float4*)(res + (size_t)t * D_))[tid];
  float4 v;
  v.x = vr.x + (a.x + bv4.x) * gw;
  v.y = vr.y + (a.y + bv4.y) * gw;
  v.z = vr.z + (a.z + bv4.z) * gw;
  v.w = vr.w + (a.w + bv4.w) * gw;
  float s = v.x + v.y + v.z + v.w;
  float sq = v.x * v.x + v.y * v.y + v.z * v.z + v.w * v.w;
#pragma unroll
  for (int o = 1; o < 64; o <<= 1) {
    s += __shfl_xor(s, o, 64);
    sq += __shfl_xor(sq, o, 64);
  }
  __shared__ float ss[4], ssq[4];
  int wave = tid >> 6, lane = tid & 63;
  if (lane == 0) { ss[wave] = s; ssq[wave] = sq; }
  __syncthreads();
  float ts = ss[0] + ss[1] + ss[2] + ss[3];
  float tsq = ssq[0] + ssq[1] + ssq[2] + ssq[3];
  float mean = ts * (1.f / D_);
  float var = tsq * (1.f / D_) - mean * mean;
  float rs = rsqrtf(var + 1e-5f);
  float4 sv = ((const float4*)S)[tid];
  float4 bi = ((const float4*)Bi)[tid];
  float4 o;
  o.x = (v.x - mean) * rs * sv.x + bi.x;
  o.y = (v.y - mean) * rs * sv.y + bi.y;
  o.z = (v.z - mean) * rs * sv.z + bi.z;
  o.w = (v.w - mean) * rs * sv.w + bi.w;
  ((float4*)(O + (size_t)t * D_))[tid] = o;
}

extern "C" void kernel_launch(void* const* d_in, const int* in_sizes, int n_in,
                              void* d_out, int out_size, void* d_ws, size_t ws_size,
                              hipStream_t stream) {
  (void)in_sizes; (void)n_in; (void)out_size; (void)ws_size;
  const float* src     = (const float*)d_in[0];
  const unsigned char* kpm = (const unsigned char*)d_in[1];
  const float* Wg_attn = (const float*)d_in[2];
  const float* Wqkv    = (const float*)d_in[3];
  const float* bqkv    = (const float*)d_in[4];
  const float* Wo      = (const float*)d_in[5];
  const float* bo      = (const float*)d_in[6];
  const float* Wg_ffn  = (const float*)d_in[7];
  const float* W1      = (const float*)d_in[8];
  const float* b1      = (const float*)d_in[9];
  const float* W2      = (const float*)d_in[10];
  const float* b2      = (const float*)d_in[11];
  const float* ln1_s   = (const float*)d_in[12];
  const float* ln1_b   = (const float*)d_in[13];
  const float* ln2_s   = (const float*)d_in[14];
  const float* ln2_b   = (const float*)d_in[15];
  float* out = (float*)d_out;

  char* ws = (char*)d_ws;
  size_t o = 0;
  auto alloc = [&](size_t bytes) -> void* {
    void* p = ws + o;
    o += (bytes + 255) & ~(size_t)255;
    return p;
  };
  int* meta = (int*)alloc(256);
  int* cnt1 = meta;
  int* off1 = meta + 8;
  int* cnt2 = meta + 17;
  int* off2 = meta + 25;
  int* idx1 = (int*)alloc(NTOK * 4);
  float* gw1 = (float*)alloc(NTOK * 4);
  int* perm1 = (int*)alloc(NTOK * 4);
  int* idx2 = (int*)alloc(NTOK * 4);
  float* gw2 = (float*)alloc(NTOK * 4);
  int* perm2 = (int*)alloc(NTOK * 4);
  unsigned short* WT = (unsigned short*)alloc((size_t)E_ * FF_ * D_ * 2);   // 67.1 MB
  unsigned short* qkvb = (unsigned short*)alloc((size_t)NTOK * 3072 * 2);   // 12.6 MB
  unsigned short* vT = (unsigned short*)alloc((size_t)32 * 64 * N_ * 2);    // 4.2 MB
  unsigned short* hbuf = qkvb;  // h[2048][4096] bf16 reuses qkv+vT (16.78 MB)
  unsigned short* ctx = (unsigned short*)alloc((size_t)NTOK * D_ * 2);      // 4.2 MB
  float* x = (float*)alloc((size_t)NTOK * D_ * 4);                          // 8.4 MB
  float* part = (float*)alloc((size_t)2 * NTOK * FF_ * 4);                  // 67.1 MB (max KS*N)

  hipMemsetAsync(meta, 0, 256, stream);

  // --- MoE attention ---
  gate_kernel<<<512, 256, 0, stream>>>(src, Wg_attn, idx1, gw1, cnt1);
  route_kernel<<<1, 256, 0, stream>>>(idx1, cnt1, off1, perm1, NTOK);
  transpose_w_kernel<<<dim3(3072 / 64, 1024 / 64, 8), 256, 0, stream>>>(Wqkv, WT, 1024, 3072);
  gemm_kernel<float, 2><<<dim3(3072 / 128, 8, 32), 256, 0, stream>>>(
      src, 1024, WT, perm1, off1, part, 1024, 3072);
  reduce_kernel<2, false, true><<<dim3(3, NTOK), 256, 0, stream>>>(
      part, bqkv, gw1, idx1, qkvb, 3072);
  vtrans_kernel<<<dim3(32, 16), 256, 0, stream>>>(qkvb, vT);
  attn_kernel<<<dim3(16, 32), 256, 0, stream>>>(qkvb, vT, kpm, ctx);
  transpose_w_kernel<<<dim3(1024 / 64, 1024 / 64, 8), 256, 0, stream>>>(Wo, WT, 1024, 1024);
  gemm_kernel<unsigned short, 4><<<dim3(1024 / 128, 8, 64), 256, 0, stream>>>(
      ctx, 1024, WT, perm1, off1, part, 1024, 1024);
  ln_reduce_kernel<4><<<NTOK, 256, 0, stream>>>(
      src, part, bo, gw1, idx1, ln1_s, ln1_b, x);

  // --- MoE FFN ---
  gate_kernel<<<512, 256, 0, stream>>>(x, Wg_ffn, idx2, gw2, cnt2);
  route_kernel<<<1, 256, 0, stream>>>(idx2, cnt2, off2, perm2, NTOK);
  transpose_w_kernel<<<dim3(4096 / 64, 1024 / 64, 8), 256, 0, stream>>>(W1, WT, 1024, 4096);
  gemm_kernel<float, 2><<<dim3(4096 / 128, 8, 32), 256, 0, stream>>>(
      x, 1024, WT, perm2, off2, part, 1024, 4096);
  reduce_kernel<2, true, true><<<dim3(4, NTOK), 256, 0, stream>>>(
      part, b1, gw2, idx2, hbuf, 4096);
  transpose_w_kernel<<<dim3(1024 / 64, 4096 / 64, 8), 256, 0, stream>>>(W2, WT, 4096, 1024);
  gemm_kernel<unsigned short, 4><<<dim3(1024 / 128, 8, 64), 256, 0, stream>>>(
      hbuf, 4096, WT, perm2, off2, part, 4096, 1024);
  ln_reduce_kernel<4><<<NTOK, 256, 0, stream>>>(
      x, part, b2, gw2, idx2, ln2_s, ln2_b, out);
}

// Round 3
// 698.920 us; speedup vs baseline: 1.1148x; 1.0705x over previous
//
#include <hip/hip_runtime.h>

// MoE Transformer encoder layer, MI355X/gfx950.
// R3: weight transpose+bf16 cast fused INTO the grouped GEMM B-staging
// (write-side LDS transpose with XOR bank swizzle) -> weights are read from
// HBM exactly once as fp32 (was: fp32 read + bf16 write + ~2x bf16 re-read).
// M-tile 256 (512-thread blocks, 8 waves) so one tile covers a typical
// expert (~256 tokens). Split-K + fp32 partials + fused reduce epilogues kept.

#define B_   2
#define N_   1024
#define D_   1024
#define H_   16
#define DH_  64
#define FF_  4096
#define E_   8
#define NTOK 2048

typedef __attribute__((ext_vector_type(8))) short short8;
typedef __attribute__((ext_vector_type(8))) unsigned short ushort8;
typedef __attribute__((ext_vector_type(4))) unsigned short ushort4v;
typedef __attribute__((ext_vector_type(4))) float f32x4;

__device__ inline unsigned short f2bf(float f) {
  unsigned u = __float_as_uint(f);
  u += 0x7FFFu + ((u >> 16) & 1u);   // round-to-nearest-even
  return (unsigned short)(u >> 16);
}

__device__ inline float gelu_tanh(float x) {
  float x3 = x * x * x;
  float t = tanhf(0.7978845608028654f * (x + 0.044715f * x3));
  return 0.5f * x * (1.0f + t);
}

// ---------------- gating: one wave per token, fp32 exact ----------------
__global__ __launch_bounds__(256) void gate_kernel(
    const float* __restrict__ X, const float* __restrict__ Wg,
    int* __restrict__ idx, float* __restrict__ gwv, int* __restrict__ cnt) {
  int t = blockIdx.x * 4 + (threadIdx.x >> 6);
  int lane = threadIdx.x & 63;
  const float* x = X + (size_t)t * D_;
  float acc[E_];
#pragma unroll
  for (int j = 0; j < E_; j++) acc[j] = 0.f;
#pragma unroll
  for (int i = 0; i < 16; i++) {
    int d = i * 64 + lane;
    float xv = x[d];
    const float4* w = (const float4*)(Wg + (size_t)d * E_);
    float4 w0 = w[0], w1 = w[1];
    acc[0] += xv * w0.x; acc[1] += xv * w0.y; acc[2] += xv * w0.z; acc[3] += xv * w0.w;
    acc[4] += xv * w1.x; acc[5] += xv * w1.y; acc[6] += xv * w1.z; acc[7] += xv * w1.w;
  }
#pragma unroll
  for (int o = 1; o < 64; o <<= 1) {
#pragma unroll
    for (int j = 0; j < E_; j++) acc[j] += __shfl_xor(acc[j], o, 64);
  }
  float m = acc[0]; int bi = 0;
#pragma unroll
  for (int j = 1; j < E_; j++) { if (acc[j] > m) { m = acc[j]; bi = j; } }
  float den = 0.f;
#pragma unroll
  for (int j = 0; j < E_; j++) den += expf(acc[j] - m);
  float gw = expf(acc[bi] - m) / den;
  if (lane == 0) { idx[t] = bi; gwv[t] = gw; atomicAdd(&cnt[bi], 1); }
}

// ---------------- routing: single block builds per-expert lists ----------------
__global__ __launch_bounds__(256) void route_kernel(
    const int* __restrict__ idx, const int* __restrict__ cnt,
    int* __restrict__ off, int* __restrict__ perm, int ntok) {
  __shared__ int loff[E_ + 1];
  __shared__ int lfill[E_];
  if (threadIdx.x == 0) {
    int s = 0;
    for (int e = 0; e < E_; e++) { loff[e] = s; s += cnt[e]; }
    loff[E_] = s;
  }
  if (threadIdx.x < E_) lfill[threadIdx.x] = 0;
  __syncthreads();
  for (int t = (int)threadIdx.x; t < ntok; t += 256) {
    int e = idx[t];
    int p = atomicAdd(&lfill[e], 1);
    perm[loff[e] + p] = t;
  }
  if (threadIdx.x < E_ + 1) off[threadIdx.x] = loff[threadIdx.x];
}

// ---------------- grouped MoE GEMM, fused weight transpose+cast ----------------
// part[kc][t][n] = A[t]·W[e][:,n] over K-chunk kc. Tiles: M=256, N=128, BK=32.
// 512 threads = 8 waves, each wave 64m x 64n (4x4 16x16x32 frags).
// W is fp32 [E][K][N] n-contiguous; staged to LDS transposed (k-contiguous)
// with bf16 cast. XOR swizzle keeps frag reads aligned b128, writes ~2-way.
template <typename AT, int KS>
__global__ __launch_bounds__(512, 2) void gemm_kernel(
    const AT* __restrict__ A, int ldA,
    const float* __restrict__ W,
    const int* __restrict__ perm, const int* __restrict__ off,
    float* __restrict__ part, int K, int N) {
  __shared__ __align__(16) unsigned short As[256][40];
  __shared__ __align__(16) unsigned short Bs[128][40];
  __shared__ int toks[256];

  int e = blockIdx.y;
  int base = off[e];
  int cnt = off[e + 1] - base;
  int mt = blockIdx.z / KS;
  int kc = blockIdx.z % KS;
  int m0 = mt * 256;
  if (m0 >= cnt) return;
  int rows_valid = min(256, cnt - m0);
  int tid = threadIdx.x;
  if (tid < 256) {
    int r = (tid < rows_valid) ? tid : (rows_valid - 1);
    toks[tid] = perm[base + m0 + r];
  }
  int nb = blockIdx.x * 128;
  int lane = tid & 63, wave = tid >> 6;
  int wm = (wave & 3) * 64, wn = (wave >> 2) * 64;
  int lr = lane & 15, lg = lane >> 4;
  f32x4 acc[4][4];
#pragma unroll
  for (int m = 0; m < 4; m++)
#pragma unroll
    for (int n = 0; n < 4; n++) acc[m][n] = (f32x4){0.f, 0.f, 0.f, 0.f};
  int srow = tid >> 1, koff = (tid & 1) * 16;   // A staging: 2 threads/row
  int k2 = (tid & 15) * 2, cB = tid >> 4;       // B staging: k-pair x 4 n
  int n0 = cB * 4;
  int KL = K / KS;
  int kbeg = kc * KL;
  __syncthreads();

  for (int k0 = kbeg; k0 < kbeg + KL; k0 += 32) {
    // ---- stage A (gathered token rows, cvt to bf16 if fp32) ----
    {
      const AT* ar = A + (size_t)toks[srow] * ldA + k0 + koff;
      ushort8 o0, o1;
      if constexpr (sizeof(AT) == 4) {
        const float* fa = (const float*)ar;
        float4 v0 = *(const float4*)(fa);
        float4 v1 = *(const float4*)(fa + 4);
        float4 v2 = *(const float4*)(fa + 8);
        float4 v3 = *(const float4*)(fa + 12);
        o0[0] = f2bf(v0.x); o0[1] = f2bf(v0.y); o0[2] = f2bf(v0.z); o0[3] = f2bf(v0.w);
        o0[4] = f2bf(v1.x); o0[5] = f2bf(v1.y); o0[6] = f2bf(v1.z); o0[7] = f2bf(v1.w);
        o1[0] = f2bf(v2.x); o1[1] = f2bf(v2.y); o1[2] = f2bf(v2.z); o1[3] = f2bf(v2.w);
        o1[4] = f2bf(v3.x); o1[5] = f2bf(v3.y); o1[6] = f2bf(v3.z); o1[7] = f2bf(v3.w);
      } else {
        o0 = *(const ushort8*)ar;
        o1 = *(const ushort8*)(ar + 8);
      }
      *(ushort8*)&As[srow][koff] = o0;
      *(ushort8*)&As[srow][koff + 8] = o1;
    }
    // ---- stage B: read 2 k-rows x 4 n fp32, cast, transposed swizzled store ----
    {
      const float* w0 = W + ((size_t)e * K + k0 + k2) * N + nb + n0;
      float4 r0 = *(const float4*)w0;
      float4 r1 = *(const float4*)(w0 + N);
      float lo[4] = {r0.x, r0.y, r0.z, r0.w};
      float hi[4] = {r1.x, r1.y, r1.z, r1.w};
#pragma unroll
      for (int j = 0; j < 4; j++) {
        int n = n0 + j;
        int sc = (((k2 >> 3) ^ ((n >> 2) & 3)) << 3) | (k2 & 7);
        unsigned v = (unsigned)f2bf(lo[j]) | ((unsigned)f2bf(hi[j]) << 16);
        *(unsigned*)&Bs[n][sc] = v;
      }
    }
    __syncthreads();
    short8 av[4], bv[4];
#pragma unroll
    for (int m = 0; m < 4; m++) av[m] = *(const short8*)&As[wm + m * 16 + lr][lg * 8];
#pragma unroll
    for (int n = 0; n < 4; n++) {
      int nn = wn + n * 16 + lr;
      int blk = lg ^ ((nn >> 2) & 3);
      bv[n] = *(const short8*)&Bs[nn][blk * 8];
    }
#pragma unroll
    for (int m = 0; m < 4; m++)
#pragma unroll
      for (int n = 0; n < 4; n++)
        acc[m][n] = __builtin_amdgcn_mfma_f32_16x16x32_bf16(av[m], bv[n], acc[m][n], 0, 0, 0);
    __syncthreads();
  }

  float* pr = part + (size_t)kc * ((size_t)NTOK * N);
#pragma unroll
  for (int n = 0; n < 4; n++) {
    int col = nb + wn + n * 16 + lr;
#pragma unroll
    for (int m = 0; m < 4; m++) {
#pragma unroll
      for (int reg = 0; reg < 4; reg++) {
        int r = wm + m * 16 + lg * 4 + reg;
        if (r < rows_valid)
          pr[(size_t)toks[r] * N + col] = acc[m][n][reg];
      }
    }
  }
}

// ---------------- reduce partials + bias + gate (+gelu), cast ----------------
template <int KS, bool GELU, bool OBF16>
__global__ __launch_bounds__(256) void reduce_kernel(
    const float* __restrict__ part, const float* __restrict__ bias,
    const float* __restrict__ gwv, const int* __restrict__ idx,
    void* __restrict__ out, int N) {
  int t = blockIdx.y;
  int n = (blockIdx.x * 256 + threadIdx.x) * 4;
  int e = idx[t];
  float gw = gwv[t];
  const float* p = part + (size_t)t * N + n;
  float4 a = *(const float4*)p;
#pragma unroll
  for (int k = 1; k < KS; k++) {
    float4 q = *(const float4*)(p + (size_t)k * NTOK * N);
    a.x += q.x; a.y += q.y; a.z += q.z; a.w += q.w;
  }
  float4 bv = *(const float4*)(bias + (size_t)e * N + n);
  a.x = (a.x + bv.x) * gw; a.y = (a.y + bv.y) * gw;
  a.z = (a.z + bv.z) * gw; a.w = (a.w + bv.w) * gw;
  if constexpr (GELU) {
    a.x = gelu_tanh(a.x); a.y = gelu_tanh(a.y);
    a.z = gelu_tanh(a.z); a.w = gelu_tanh(a.w);
  }
  if constexpr (OBF16) {
    ushort4v o;
    o[0] = f2bf(a.x); o[1] = f2bf(a.y); o[2] = f2bf(a.z); o[3] = f2bf(a.w);
    *(ushort4v*)((unsigned short*)out + (size_t)t * N + n) = o;
  } else {
    *(float4*)((float*)out + (size_t)t * N + n) = a;
  }
}

// ---------------- V transpose per (b,h) ----------------
__global__ __launch_bounds__(256) void vtrans_kernel(
    const unsigned short* __restrict__ qkv, unsigned short* __restrict__ vT) {
  __shared__ __align__(16) unsigned short T[64][72];
  int bh = blockIdx.x;
  int b = bh >> 4, h = bh & 15;
  int tile = blockIdx.y;
  int tid = threadIdx.x;
  {
    int tk = tid >> 2, dof = (tid & 3) * 16;
    const unsigned short* p =
        qkv + ((size_t)(b * N_ + tile * 64 + tk)) * 3072 + 2048 + h * 64 + dof;
    *(ushort8*)&T[tk][dof] = *(const ushort8*)p;
    *(ushort8*)&T[tk][dof + 8] = *(const ushort8*)(p + 8);
  }
  __syncthreads();
  {
    int dh = tid >> 2, tof = (tid & 3) * 16;
    ushort8 o0, o1;
#pragma unroll
    for (int i = 0; i < 8; i++) o0[i] = T[tof + i][dh];
#pragma unroll
    for (int i = 0; i < 8; i++) o1[i] = T[tof + 8 + i][dh];
    unsigned short* q = vT + ((size_t)bh * 64 + dh) * N_ + tile * 64 + tof;
    *(ushort8*)q = o0;
    *(ushort8*)(q + 8) = o1;
  }
}

// ---------------- flash attention ----------------
__global__ __launch_bounds__(256) void attn_kernel(
    const unsigned short* __restrict__ qkv, const unsigned short* __restrict__ vT,
    const unsigned char* __restrict__ kpm, unsigned short* __restrict__ ctx) {
  __shared__ __align__(16) unsigned short Qs[64][72];
  __shared__ __align__(16) unsigned short Ks[64][72];
  __shared__ __align__(16) unsigned short Vs[64][72];
  __shared__ __align__(16) unsigned short Ps[4][16][72];
  __shared__ float maskf[64];
  int qt = blockIdx.x, bh = blockIdx.y;
  int b = bh >> 4, h = bh & 15;
  int tid = threadIdx.x, lane = tid & 63, wave = tid >> 6;
  int lr = lane & 15, lg = lane >> 4;
  {
    int r = tid >> 2, dof = (tid & 3) * 16;
    const unsigned short* p = qkv + ((size_t)(b * N_ + qt * 64 + r)) * 3072 + h * 64 + dof;
    *(ushort8*)&Qs[r][dof] = *(const ushort8*)p;
    *(ushort8*)&Qs[r][dof + 8] = *(const ushort8*)(p + 8);
  }
  __syncthreads();
  short8 aq[2];
  aq[0] = *(const short8*)&Qs[wave * 16 + lr][lg * 8];
  aq[1] = *(const short8*)&Qs[wave * 16 + lr][32 + lg * 8];
  f32x4 O[4];
  float mrun[4], lrun[4];
#pragma unroll
  for (int r = 0; r < 4; r++) { mrun[r] = -1e30f; lrun[r] = 0.f; O[r] = (f32x4){0.f, 0.f, 0.f, 0.f}; }

  for (int kt = 0; kt < 16; kt++) {
    __syncthreads();
    {
      int r = tid >> 2, dof = (tid & 3) * 16;
      const unsigned short* p =
          qkv + ((size_t)(b * N_ + kt * 64 + r)) * 3072 + 1024 + h * 64 + dof;
      *(ushort8*)&Ks[r][dof] = *(const ushort8*)p;
      *(ushort8*)&Ks[r][dof + 8] = *(const ushort8*)(p + 8);
      const unsigned short* pv = vT + ((size_t)bh * 64 + r) * N_ + kt * 64 + dof;
      *(ushort8*)&Vs[r][dof] = *(const ushort8*)pv;
      *(ushort8*)&Vs[r][dof + 8] = *(const ushort8*)(pv + 8);
      if (tid < 64) maskf[tid] = kpm[b * N_ + kt * 64 + tid] ? -10000.f : 0.f;
    }
    __syncthreads();
    f32x4 S[4];
#pragma unroll
    for (int n = 0; n < 4; n++) {
      f32x4 s = (f32x4){0.f, 0.f, 0.f, 0.f};
#pragma unroll
      for (int ks = 0; ks < 2; ks++) {
        short8 bk = *(const short8*)&Ks[n * 16 + lr][ks * 32 + lg * 8];
        s = __builtin_amdgcn_mfma_f32_16x16x32_bf16(aq[ks], bk, s, 0, 0, 0);
      }
      float mv = maskf[n * 16 + lr];
#pragma unroll
      for (int r = 0; r < 4; r++) s[r] = s[r] * 0.125f + mv;
      S[n] = s;
    }
    float cur[4];
#pragma unroll
    for (int r = 0; r < 4; r++)
      cur[r] = fmaxf(fmaxf(S[0][r], S[1][r]), fmaxf(S[2][r], S[3][r]));
#pragma unroll
    for (int o = 1; o < 16; o <<= 1) {
#pragma unroll
      for (int r = 0; r < 4; r++) cur[r] = fmaxf(cur[r], __shfl_xor(cur[r], o, 64));
    }
    float alpha[4], rsum[4];
#pragma unroll
    for (int r = 0; r < 4; r++) {
      float mn = fmaxf(mrun[r], cur[r]);
      alpha[r] = expf(mrun[r] - mn);
      mrun[r] = mn;
      rsum[r] = 0.f;
    }
#pragma unroll
    for (int n = 0; n < 4; n++) {
#pragma unroll
      for (int r = 0; r < 4; r++) {
        S[n][r] = expf(S[n][r] - mrun[r]);
        rsum[r] += S[n][r];
      }
    }
#pragma unroll
    for (int o = 1; o < 16; o <<= 1) {
#pragma unroll
      for (int r = 0; r < 4; r++) rsum[r] += __shfl_xor(rsum[r], o, 64);
    }
#pragma unroll
    for (int r = 0; r < 4; r++) lrun[r] = lrun[r] * alpha[r] + rsum[r];
#pragma unroll
    for (int d = 0; d < 4; d++)
#pragma unroll
      for (int r = 0; r < 4; r++) O[d][r] *= alpha[r];
#pragma unroll
    for (int n = 0; n < 4; n++)
#pragma unroll
      for (int r = 0; r < 4; r++) Ps[wave][lg * 4 + r][n * 16 + lr] = f2bf(S[n][r]);
    short8 pf[2];
    pf[0] = *(const short8*)&Ps[wave][lr][lg * 8];
    pf[1] = *(const short8*)&Ps[wave][lr][32 + lg * 8];
#pragma unroll
    for (int d = 0; d < 4; d++) {
#pragma unroll
      for (int ks = 0; ks < 2; ks++) {
        short8 bv = *(const short8*)&Vs[d * 16 + lr][ks * 32 + lg * 8];
        O[d] = __builtin_amdgcn_mfma_f32_16x16x32_bf16(pf[ks], bv, O[d], 0, 0, 0);
      }
    }
  }
#pragma unroll
  for (int r = 0; r < 4; r++) lrun[r] = 1.f / lrun[r];
#pragma unroll
  for (int d = 0; d < 4; d++) {
#pragma unroll
    for (int r = 0; r < 4; r++) {
      int q = qt * 64 + wave * 16 + lg * 4 + r;
      int dh = d * 16 + lr;
      ctx[((size_t)(b * N_ + q)) * D_ + h * DH_ + dh] = f2bf(O[d][r] * lrun[r]);
    }
  }
}

// ---------------- fused: out = LN(res + (Σ part + bias)·gw) ----------------
template <int KS>
__global__ __launch_bounds__(256) void ln_reduce_kernel(
    const float* __restrict__ res, const float* __restrict__ part,
    const float* __restrict__ bias, const float* __restrict__ gwv,
    const int* __restrict__ idx,
    const float* __restrict__ S, const float* __restrict__ Bi,
    float* __restrict__ O) {
  int t = blockIdx.x, tid = threadIdx.x;
  int e = idx[t];
  float gw = gwv[t];
  const float* p = part + (size_t)t * D_ + tid * 4;
  float4 a = *(const float4*)p;
#pragma unroll
  for (int k = 1; k < KS; k++) {
    float4 q = *(const float4*)(p + (size_t)k * NTOK * D_);
    a.x += q.x; a.y += q.y; a.z += q.z; a.w += q.w;
  }
  float4 bv4 = *(const float4*)(bias + (size_t)e * D_ + tid * 4);
  float4 vr = ((const float4*)(res + (size_t)t * D_))[tid];
  float4 v;
  v.x = vr.x + (a.x + bv4.x) * gw;
  v.y = vr.y + (a.y + bv4.y) * gw;
  v.z = vr.z + (a.z + bv4.z) * gw;
  v.w = vr.w + (a.w + bv4.w) * gw;
  float s = v.x + v.y + v.z + v.w;
  float sq = v.x * v.x + v.y * v.y + v.z * v.z + v.w * v.w;
#pragma unroll
  for (int o = 1; o < 64; o <<= 1) {
    s += __shfl_xor(s, o, 64);
    sq += __shfl_xor(sq, o, 64);
  }
  __shared__ float ss[4], ssq[4];
  int wave = tid >> 6, lane = tid & 63;
  if (lane == 0) { ss[wave] = s; ssq[wave] = sq; }
  __syncthreads();
  float ts = ss[0] + ss[1] + ss[2] + ss[3];
  float tsq = ssq[0] + ssq[1] + ssq[2] + ssq[3];
  float mean = ts * (1.f / D_);
  float var = tsq * (1.f / D_) - mean * mean;
  float rs = rsqrtf(var + 1e-5f);
  float4 sv = ((const float4*)S)[tid];
  float4 bi = ((const float4*)Bi)[tid];
  float4 o;
  o.x = (v.x - mean) * rs * sv.x + bi.x;
  o.y = (v.y - mean) * rs * sv.y + bi.y;
  o.z = (v.z - mean) * rs * sv.z + bi.z;
  o.w = (v.w - mean) * rs * sv.w + bi.w;
  ((float4*)(O + (size_t)t * D_))[tid] = o;
}

extern "C" void kernel_launch(void* const* d_in, const int* in_sizes, int n_in,
                              void* d_out, int out_size, void* d_ws, size_t ws_size,
                              hipStream_t stream) {
  (void)in_sizes; (void)n_in; (void)out_size; (void)ws_size;
  const float* src     = (const float*)d_in[0];
  const unsigned char* kpm = (const unsigned char*)d_in[1];
  const float* Wg_attn = (const float*)d_in[2];
  const float* Wqkv    = (const float*)d_in[3];
  const float* bqkv    = (const float*)d_in[4];
  const float* Wo      = (const float*)d_in[5];
  const float* bo      = (const float*)d_in[6];
  const float* Wg_ffn  = (const float*)d_in[7];
  const float* W1      = (const float*)d_in[8];
  const float* b1      = (const float*)d_in[9];
  const float* W2      = (const float*)d_in[10];
  const float* b2      = (const float*)d_in[11];
  const float* ln1_s   = (const float*)d_in[12];
  const float* ln1_b   = (const float*)d_in[13];
  const float* ln2_s   = (const float*)d_in[14];
  const float* ln2_b   = (const float*)d_in[15];
  float* out = (float*)d_out;

  char* ws = (char*)d_ws;
  size_t o = 0;
  auto alloc = [&](size_t bytes) -> void* {
    void* p = ws + o;
    o += (bytes + 255) & ~(size_t)255;
    return p;
  };
  int* meta = (int*)alloc(256);
  int* cnt1 = meta;
  int* off1 = meta + 8;
  int* cnt2 = meta + 17;
  int* off2 = meta + 25;
  int* idx1 = (int*)alloc(NTOK * 4);
  float* gw1 = (float*)alloc(NTOK * 4);
  int* perm1 = (int*)alloc(NTOK * 4);
  int* idx2 = (int*)alloc(NTOK * 4);
  float* gw2 = (float*)alloc(NTOK * 4);
  int* perm2 = (int*)alloc(NTOK * 4);
  unsigned short* qkvb = (unsigned short*)alloc((size_t)NTOK * 3072 * 2);   // 12.6 MB
  unsigned short* vT = (unsigned short*)alloc((size_t)32 * 64 * N_ * 2);    // 4.2 MB
  unsigned short* hbuf = qkvb;  // h[2048][4096] bf16 reuses qkv+vT (16.78 MB)
  unsigned short* ctx = (unsigned short*)alloc((size_t)NTOK * D_ * 2);      // 4.2 MB
  float* x = (float*)alloc((size_t)NTOK * D_ * 4);                          // 8.4 MB
  float* part = (float*)alloc((size_t)2 * NTOK * FF_ * 4);                  // 67.1 MB (max KS*N)

  hipMemsetAsync(meta, 0, 256, stream);

  // --- MoE attention ---
  gate_kernel<<<512, 256, 0, stream>>>(src, Wg_attn, idx1, gw1, cnt1);
  route_kernel<<<1, 256, 0, stream>>>(idx1, cnt1, off1, perm1, NTOK);
  gemm_kernel<float, 2><<<dim3(3072 / 128, 8, 16), 512, 0, stream>>>(
      src, 1024, Wqkv, perm1, off1, part, 1024, 3072);
  reduce_kernel<2, false, true><<<dim3(3, NTOK), 256, 0, stream>>>(
      part, bqkv, gw1, idx1, qkvb, 3072);
  vtrans_kernel<<<dim3(32, 16), 256, 0, stream>>>(qkvb, vT);
  attn_kernel<<<dim3(16, 32), 256, 0, stream>>>(qkvb, vT, kpm, ctx);
  gemm_kernel<unsigned short, 4><<<dim3(1024 / 128, 8, 32), 512, 0, stream>>>(
      ctx, 1024, Wo, perm1, off1, part, 1024, 1024);
  ln_reduce_kernel<4><<<NTOK, 256, 0, stream>>>(
      src, part, bo, gw1, idx1, ln1_s, ln1_b, x);

  // --- MoE FFN ---
  gate_kernel<<<512, 256, 0, stream>>>(x, Wg_ffn, idx2, gw2, cnt2);
  route_kernel<<<1, 256, 0, stream>>>(idx2, cnt2, off2, perm2, NTOK);
  gemm_kernel<float, 2><<<dim3(4096 / 128, 8, 16), 512, 0, stream>>>(
      x, 1024, W1, perm2, off2, part, 1024, 4096);
  reduce_kernel<2, true, true><<<dim3(4, NTOK), 256, 0, stream>>>(
      part, b1, gw2, idx2, hbuf, 4096);
  gemm_kernel<unsigned short, 4><<<dim3(1024 / 128, 8, 32), 512, 0, stream>>>(
      hbuf, 4096, W2, perm2, off2, part, 4096, 1024);
  ln_reduce_kernel<4><<<NTOK, 256, 0, stream>>>(
      x, part, b2, gw2, idx2, ln2_s, ln2_b, out);
}